// Round 11
// baseline (366.525 us; speedup 1.0000x reference)
//
#include <hip/hip_runtime.h>
#include <hip/hip_bf16.h>

// Problem constants: B=16, T=512, H=1024, L=8192, D=256
// logits[b,l] = sum_t softmax_t(Q[l]·K[b,t]/16) * (Wout[l]·V[b,t]) + bias[l]

typedef __bf16 bf16x8 __attribute__((ext_vector_type(8)));
typedef float f32x4 __attribute__((ext_vector_type(4)));

__device__ __forceinline__ unsigned short f2bf(float f) {
    // round-to-nearest-even fp32 -> bf16 (finite inputs only)
    unsigned int u = __builtin_bit_cast(unsigned int, f);
    unsigned int lsb = (u >> 16) & 1u;
    u += 0x7fffu + lsb;
    return (unsigned short)(u >> 16);
}

// async global->LDS DMA: each lane contributes 16 B; LDS dest = wave-uniform
// base + lane*16 (m104/m108). Global source IS per-lane -> swizzled layouts
// are achieved by pre-swizzling the per-lane source address (rule #21).
__device__ __forceinline__ void gld_lds16(const void* g, void* l) {
    __builtin_amdgcn_global_load_lds((__attribute__((address_space(1))) void*)g,
                                     (__attribute__((address_space(3))) void*)l,
                                     16, 0, 0);
}

// -----------------------------------------------------------------------------
// Fused fp32->bf16 conversion for all five tensors in one launch.
// Q segment is pre-scaled by log2(e)/16: folds the softmax 1/sqrt(D) scale AND
// the exp->exp2 conversion out of the attention inner loop (verified r2/r5).
// Segments (float4 units): X 2097152 | Q 524288 | Wo 524288 | Wk 65536 | Wv 65536
// -----------------------------------------------------------------------------
__global__ __launch_bounds__(256) void cvt_all(const float* __restrict__ X,
                                               const float* __restrict__ Q,
                                               const float* __restrict__ Wo,
                                               const float* __restrict__ Wk,
                                               const float* __restrict__ Wv,
                                               unsigned short* __restrict__ dst) {
    int base = blockIdx.x * 1024 + threadIdx.x;
#pragma unroll
    for (int r = 0; r < 4; ++r) {
        int idx = base + r * 256;  // float4 index, < 3276800
        const float* src;
        int off;
        float s = 1.0f;
        if (idx < 2097152)      { src = X;  off = idx; }
        else if (idx < 2621440) { src = Q;  off = idx - 2097152; s = 0.09016844006f; }
        else if (idx < 3145728) { src = Wo; off = idx - 2621440; }
        else if (idx < 3211264) { src = Wk; off = idx - 3145728; }
        else                    { src = Wv; off = idx - 3211264; }
        float4 v = ((const float4*)src)[off];
        ushort4 o;
        o.x = f2bf(v.x * s); o.y = f2bf(v.y * s);
        o.z = f2bf(v.z * s); o.w = f2bf(v.w * s);
        ((ushort4*)dst)[idx] = o;
    }
}

// -----------------------------------------------------------------------------
// Phase 1: K,V projection (r9 version — DMA-staged, double-buffered, verified).
// C[m][n] = sum_h X[m][h]*Wkv[n][h]; M=8192, N=512, K=1024.
// Tile 128x128, grid 64x4, 4 waves 2x2, LDS 2x(16+16) KB, XOR granule swizzle.
// -----------------------------------------------------------------------------
__global__ __launch_bounds__(256) void kv_gemm(const unsigned short* __restrict__ Xb,
                                               const unsigned short* __restrict__ Wb,
                                               unsigned short* __restrict__ Kb,
                                               unsigned short* __restrict__ Vb) {
    __shared__ unsigned short Xs[2][128 * 64];  // row-major, granule-swizzled
    __shared__ unsigned short Ws[2][128 * 64];
    const int bid = blockIdx.x;
    const int nt = bid & 3, mt = bid >> 2;
    const int m0 = mt * 128, n0 = nt * 128;
    const int tid = threadIdx.x;
    const int lane = tid & 63, w = tid >> 6;
    const int q = lane >> 4, ln = lane & 15;
    const int wm = (w & 1) * 64, wn = (w >> 1) * 64;
    const int lrow = lane >> 3;            // 0..7 within the 8-row DMA span
    const int gsw  = (lane & 7) ^ lrow;    // pre-swizzled source granule

    f32x4 acc[4][4];
#pragma unroll
    for (int mi = 0; mi < 4; ++mi)
#pragma unroll
        for (int ni = 0; ni < 4; ++ni) acc[mi][ni] = f32x4{0.f, 0.f, 0.f, 0.f};

    auto stage = [&](int hc) {
        const int p = hc & 1;
        const int h0 = hc * 64;
#pragma unroll
        for (int j = 0; j < 4; ++j) {
            int slot = w * 4 + j;          // wave-uniform, 0..15
            int r = slot * 8 + lrow;       // local row 0..127
            gld_lds16(Xb + (size_t)(m0 + r) * 1024 + h0 + gsw * 8,
                      &Xs[p][slot * 512]);
            gld_lds16(Wb + (size_t)(n0 + r) * 1024 + h0 + gsw * 8,
                      &Ws[p][slot * 512]);
        }
    };
    stage(0);

#pragma unroll 1
    for (int hc = 0; hc < 16; ++hc) {
        asm volatile("s_waitcnt vmcnt(0)" ::: "memory");
        __syncthreads();            // chunk hc landed; parity hc&1 reusable
        if (hc < 15) stage(hc + 1); // prefetch lands during compute below
        const int p = hc & 1;
#pragma unroll
        for (int ks = 0; ks < 64; ks += 32) {
            bf16x8 a[4], b[4];
#pragma unroll
            for (int mi = 0; mi < 4; ++mi) {
                int r = wm + mi * 16 + ln;
                int g = ((ks >> 3) + q) ^ (r & 7);   // swizzled granule
                a[mi] = *(const bf16x8*)(&Xs[p][r * 64 + g * 8]);
            }
#pragma unroll
            for (int ni = 0; ni < 4; ++ni) {
                int r = wn + ni * 16 + ln;
                int g = ((ks >> 3) + q) ^ (r & 7);
                b[ni] = *(const bf16x8*)(&Ws[p][r * 64 + g * 8]);
            }
#pragma unroll
            for (int mi = 0; mi < 4; ++mi)
#pragma unroll
                for (int ni = 0; ni < 4; ++ni)
                    acc[mi][ni] = __builtin_amdgcn_mfma_f32_16x16x32_bf16(
                        a[mi], b[ni], acc[mi][ni], 0, 0, 0);
        }
        __syncthreads();            // all reads of parity p done before restage
    }
    // epilogue: C/D layout col(=n) = ln, row(=m) = q*4+reg
    {
        unsigned short* dst = (n0 < 256) ? Kb : Vb;  // uniform per block
        const int d0 = (n0 & 255) + wn;
#pragma unroll
        for (int mi = 0; mi < 4; ++mi)
#pragma unroll
            for (int ni = 0; ni < 4; ++ni) {
                int d = d0 + ni * 16 + ln;
#pragma unroll
                for (int r = 0; r < 4; ++r) {
                    int m = m0 + wm + mi * 16 + q * 4 + r;
                    dst[m * 256 + d] = f2bf(acc[mi][ni][r]);
                }
            }
    }
}

// -----------------------------------------------------------------------------
// Phase 2: fused S = Q·K^T, P = Wout·V^T, softmax-weighted reduce over t.
// Round-16: r5 per-wave body EXACTLY (16x16x32 MFMA with 8 independent acc
// chains — r10's 32x32 single-chain variant lost 6% to MFMA latency; reverted)
// with ONE structural change: 512-thread blocks sharing ONE staging copy.
//   r5: 2 co-resident 256-thread blocks per CU staged IDENTICAL K/V into two
//       private LDS copies, 2 waves/SIMD, LDS port ~63% utilized, ~2400
//       cyc/phase idle (port accounting vs measured phase time).
//   now: 8 waves/block x 32 l = 256 l per block; one 64 KB double-buffered
//       staging copy serves all 8 waves (DMA + LDS-write per l HALVED); 2
//       blocks/CU (128 KB LDS) -> 4 waves/SIMD to saturate the LDS port,
//       2 independent barrier groups to break lockstep.
// __launch_bounds__(512,4) caps VGPR at 128 (r5 measured 120 -> fits).
// Same staged values, same per-wave compute order -> output bit-identical.
// Grid = 16 b x 32 = 512 blocks.
// -----------------------------------------------------------------------------
__global__ __launch_bounds__(512, 4) void attn_fused(const unsigned short* __restrict__ Qb,
                                                     const unsigned short* __restrict__ Wob,
                                                     const unsigned short* __restrict__ Kb,
                                                     const unsigned short* __restrict__ Vb,
                                                     const int* __restrict__ mask,
                                                     const float* __restrict__ bias,
                                                     float* __restrict__ out) {
    __shared__ unsigned short Ks[2][8192];  // 32 rows x 256 ushorts, XOR-swizzled granules
    __shared__ unsigned short Vs[2][8192];
    const int bid = blockIdx.x;
    const int bb = bid >> 5;             // batch
    const int l0 = (bid & 31) * 256;     // l-tile origin (256 l per block)
    const int tid = threadIdx.x;
    const int lane = tid & 63, w = tid >> 6;   // w = 32-l strip 0..7
    const int q = lane >> 4, ln = lane & 15;
    const int hi = lane >> 5, lo = lane & 31;  // DMA row-half / granule slot

    // DMA-stage chunk c (32t x 256d of K and V) into parity c&1.
    // 32 row-pair groups (K: 0..15, V: 16..31); each of 8 waves issues 4.
    // Group g covers rows 2g,2g+1 (1 KB contiguous); lane i fetches source
    // granule (lo ^ t) of row t = 2g+hi so LDS granule gl holds gd = gl ^ t.
    auto stage = [&](int c) {
        const int p = c & 1;
        const int rbase = bb * 512 + c * 32;
#pragma unroll
        for (int j = 0; j < 4; ++j) {
            int gid = w * 4 + j;        // wave-uniform, 0..31
            int g = gid & 15;           // row-pair index
            const unsigned short* srcb = (gid < 16) ? Kb : Vb;
            unsigned short* dstb = (gid < 16) ? &Ks[p][0] : &Vs[p][0];
            int tl = 2 * g + hi;        // local t-row 0..31
            gld_lds16(srcb + (size_t)(rbase + tl) * 256 + ((lo ^ tl) << 3),
                      dstb + g * 512);
        }
    };
    stage(0);   // overlaps the register prologue below

    // Prologue 1: per-lane mask bits. t = 16*(2c+ni) + ln  ->  bit j = 2c+ni.
    unsigned mbits = 0;
    {
        const int* mrow = mask + bb * 512;
#pragma unroll
        for (int j = 0; j < 32; ++j)
            mbits |= (mrow[j * 16 + ln] != 0 ? 1u : 0u) << j;
    }

    // Prologue 2: A-fragments for 32 l-rows x full d=256 (8 k-steps) in regs.
    bf16x8 aQ[2][8], aW[2][8];
#pragma unroll
    for (int mi = 0; mi < 2; ++mi) {
        const int row = (l0 + w * 32 + mi * 16 + ln) * 256;
#pragma unroll
        for (int kk = 0; kk < 8; ++kk) {
            aQ[mi][kk] = *(const bf16x8*)(&Qb[row + kk * 32 + q * 8]);
            aW[mi][kk] = *(const bf16x8*)(&Wob[row + kk * 32 + q * 8]);
        }
    }

    float num[2][4], den[2][4];
#pragma unroll
    for (int mi = 0; mi < 2; ++mi)
#pragma unroll
        for (int r = 0; r < 4; ++r) { num[mi][r] = 0.f; den[mi][r] = 0.f; }

#pragma unroll 1
    for (int c = 0; c < 16; ++c) {
        // Hard guarantee: all in-flight global_load_lds DMAs (stage(c)) landed
        // before the barrier (round-3 race fix; verified round 4/5).
        asm volatile("s_waitcnt vmcnt(0)" ::: "memory");
        __syncthreads();           // chunk c ready; parity c&1 reusable
        if (c < 15) stage(c + 1);  // prefetch lands during compute below
        const int p = c & 1;

        f32x4 Sa[2][2], Pa[2][2];
#pragma unroll
        for (int mi = 0; mi < 2; ++mi)
#pragma unroll
            for (int ni = 0; ni < 2; ++ni) {
                Sa[mi][ni] = f32x4{0.f, 0.f, 0.f, 0.f};
                Pa[mi][ni] = f32x4{0.f, 0.f, 0.f, 0.f};
            }

#pragma unroll
        for (int kk = 0; kk < 8; ++kk) {
            bf16x8 bK[2], bV[2];
#pragma unroll
            for (int ni = 0; ni < 2; ++ni) {
                const int t = ni * 16 + ln;                       // row in chunk
                const int off = t * 256 + (((kk * 4 + q) ^ t) << 3);  // swizzled granule
                bK[ni] = *(const bf16x8*)(&Ks[p][off]);
                bV[ni] = *(const bf16x8*)(&Vs[p][off]);
            }
#pragma unroll
            for (int mi = 0; mi < 2; ++mi)
#pragma unroll
                for (int ni = 0; ni < 2; ++ni) {
                    Sa[mi][ni] = __builtin_amdgcn_mfma_f32_16x16x32_bf16(
                        aQ[mi][kk], bK[ni], Sa[mi][ni], 0, 0, 0);
                    Pa[mi][ni] = __builtin_amdgcn_mfma_f32_16x16x32_bf16(
                        aW[mi][kk], bV[ni], Pa[mi][ni], 0, 0, 0);
                }
        }
        // softmax partials. D layout: col(=t) = ln, row(=l) = q*4+r.
        // Q pre-scaled by log2(e)/16; S small: exp2 w/o max-shift is exact.
#pragma unroll
        for (int ni = 0; ni < 2; ++ni) {
            bool ok = (mbits >> (c * 2 + ni)) & 1u;
#pragma unroll
            for (int mi = 0; mi < 2; ++mi)
#pragma unroll
                for (int r = 0; r < 4; ++r) {
                    float e = ok ? __builtin_amdgcn_exp2f(Sa[mi][ni][r]) : 0.0f;
                    den[mi][r] += e;
                    num[mi][r] += e * Pa[mi][ni][r];
                }
        }
    }

    // reduce over the 16 t-columns (lanes ln) of each quad group; each wave
    // covered all 512 t, so no cross-wave reduction is needed.
#pragma unroll
    for (int mi = 0; mi < 2; ++mi)
#pragma unroll
        for (int r = 0; r < 4; ++r) {
            float n_ = num[mi][r], d_ = den[mi][r];
#pragma unroll
            for (int o = 1; o < 16; o <<= 1) {
                n_ += __shfl_xor(n_, o);
                d_ += __shfl_xor(d_, o);
            }
            if (ln == 0) {
                int l = l0 + w * 32 + mi * 16 + q * 4 + r;
                out[bb * 8192 + l] = n_ / d_ + bias[l];
            }
        }
}

extern "C" void kernel_launch(void* const* d_in, const int* in_sizes, int n_in,
                              void* d_out, int out_size, void* d_ws, size_t ws_size,
                              hipStream_t stream) {
    const float* X    = (const float*)d_in[0];  // [16,512,1024]
    const int*   mask = (const int*)d_in[1];    // [16,512]
    const float* Q    = (const float*)d_in[2];  // [8192,256]
    const float* Wk   = (const float*)d_in[3];  // [256,1024]
    const float* Wv   = (const float*)d_in[4];  // [256,1024]
    const float* Wo   = (const float*)d_in[5];  // [8192,256]
    const float* bias = (const float*)d_in[6];  // [8192]
    float* out = (float*)d_out;                 // [16,8192]

    unsigned short* Xb   = (unsigned short*)d_ws;          // 8,388,608 elems
    unsigned short* Qb   = Xb + 8388608ull;                // 2,097,152 (Q * log2e/16)
    unsigned short* Wob  = Qb + 2097152ull;                // 2,097,152
    unsigned short* Wkvb = Wob + 2097152ull;               // 524,288 (Wk 0-255, Wv 256-511)
    unsigned short* Kb   = Wkvb + 524288ull;               // 2,097,152
    unsigned short* Vb   = Kb + 2097152ull;                // 2,097,152  (total ~34.6 MB)

    cvt_all<<<dim3(3200), 256, 0, stream>>>(X, Q, Wo, Wk, Wv, Xb);
    kv_gemm<<<dim3(256), 256, 0, stream>>>(Xb, Wkvb, Kb, Vb);
    attn_fused<<<dim3(512), 512, 0, stream>>>(Qb, Wob, Kb, Vb, mask, bias, out);
}

// Round 12
// 194.602 us; speedup vs baseline: 1.8835x; 1.8835x over previous
//
#include <hip/hip_runtime.h>
#include <hip/hip_bf16.h>

// Problem constants: B=16, T=512, H=1024, L=8192, D=256
// logits[b,l] = sum_t softmax_t(Q[l]·K[b,t]/16) * (Wout[l]·V[b,t]) + bias[l]

typedef __bf16 bf16x8 __attribute__((ext_vector_type(8)));
typedef float f32x4 __attribute__((ext_vector_type(4)));

__device__ __forceinline__ unsigned short f2bf(float f) {
    // round-to-nearest-even fp32 -> bf16 (finite inputs only)
    unsigned int u = __builtin_bit_cast(unsigned int, f);
    unsigned int lsb = (u >> 16) & 1u;
    u += 0x7fffu + lsb;
    return (unsigned short)(u >> 16);
}

// async global->LDS DMA: each lane contributes 16 B; LDS dest = wave-uniform
// base + lane*16 (m104/m108). Global source IS per-lane -> swizzled layouts
// are achieved by pre-swizzling the per-lane source address (rule #21).
__device__ __forceinline__ void gld_lds16(const void* g, void* l) {
    __builtin_amdgcn_global_load_lds((__attribute__((address_space(1))) void*)g,
                                     (__attribute__((address_space(3))) void*)l,
                                     16, 0, 0);
}

// -----------------------------------------------------------------------------
// Fused fp32->bf16 conversion for all five tensors in one launch.
// Q segment is pre-scaled by log2(e)/16: folds the softmax 1/sqrt(D) scale AND
// the exp->exp2 conversion out of the attention inner loop (verified r2/r5).
// Segments (float4 units): X 2097152 | Q 524288 | Wo 524288 | Wk 65536 | Wv 65536
// -----------------------------------------------------------------------------
__global__ __launch_bounds__(256) void cvt_all(const float* __restrict__ X,
                                               const float* __restrict__ Q,
                                               const float* __restrict__ Wo,
                                               const float* __restrict__ Wk,
                                               const float* __restrict__ Wv,
                                               unsigned short* __restrict__ dst) {
    int base = blockIdx.x * 1024 + threadIdx.x;
#pragma unroll
    for (int r = 0; r < 4; ++r) {
        int idx = base + r * 256;  // float4 index, < 3276800
        const float* src;
        int off;
        float s = 1.0f;
        if (idx < 2097152)      { src = X;  off = idx; }
        else if (idx < 2621440) { src = Q;  off = idx - 2097152; s = 0.09016844006f; }
        else if (idx < 3145728) { src = Wo; off = idx - 2621440; }
        else if (idx < 3211264) { src = Wk; off = idx - 3145728; }
        else                    { src = Wv; off = idx - 3211264; }
        float4 v = ((const float4*)src)[off];
        ushort4 o;
        o.x = f2bf(v.x * s); o.y = f2bf(v.y * s);
        o.z = f2bf(v.z * s); o.w = f2bf(v.w * s);
        ((ushort4*)dst)[idx] = o;
    }
}

// -----------------------------------------------------------------------------
// Phase 1: K,V projection (r9 version — DMA-staged, double-buffered, verified).
// C[m][n] = sum_h X[m][h]*Wkv[n][h]; M=8192, N=512, K=1024.
// Tile 128x128, grid 64x4, 4 waves 2x2, LDS 2x(16+16) KB, XOR granule swizzle.
// -----------------------------------------------------------------------------
__global__ __launch_bounds__(256) void kv_gemm(const unsigned short* __restrict__ Xb,
                                               const unsigned short* __restrict__ Wb,
                                               unsigned short* __restrict__ Kb,
                                               unsigned short* __restrict__ Vb) {
    __shared__ unsigned short Xs[2][128 * 64];  // row-major, granule-swizzled
    __shared__ unsigned short Ws[2][128 * 64];
    const int bid = blockIdx.x;
    const int nt = bid & 3, mt = bid >> 2;
    const int m0 = mt * 128, n0 = nt * 128;
    const int tid = threadIdx.x;
    const int lane = tid & 63, w = tid >> 6;
    const int q = lane >> 4, ln = lane & 15;
    const int wm = (w & 1) * 64, wn = (w >> 1) * 64;
    const int lrow = lane >> 3;            // 0..7 within the 8-row DMA span
    const int gsw  = (lane & 7) ^ lrow;    // pre-swizzled source granule

    f32x4 acc[4][4];
#pragma unroll
    for (int mi = 0; mi < 4; ++mi)
#pragma unroll
        for (int ni = 0; ni < 4; ++ni) acc[mi][ni] = f32x4{0.f, 0.f, 0.f, 0.f};

    auto stage = [&](int hc) {
        const int p = hc & 1;
        const int h0 = hc * 64;
#pragma unroll
        for (int j = 0; j < 4; ++j) {
            int slot = w * 4 + j;          // wave-uniform, 0..15
            int r = slot * 8 + lrow;       // local row 0..127
            gld_lds16(Xb + (size_t)(m0 + r) * 1024 + h0 + gsw * 8,
                      &Xs[p][slot * 512]);
            gld_lds16(Wb + (size_t)(n0 + r) * 1024 + h0 + gsw * 8,
                      &Ws[p][slot * 512]);
        }
    };
    stage(0);

#pragma unroll 1
    for (int hc = 0; hc < 16; ++hc) {
        asm volatile("s_waitcnt vmcnt(0)" ::: "memory");
        __syncthreads();            // chunk hc landed; parity hc&1 reusable
        if (hc < 15) stage(hc + 1); // prefetch lands during compute below
        const int p = hc & 1;
#pragma unroll
        for (int ks = 0; ks < 64; ks += 32) {
            bf16x8 a[4], b[4];
#pragma unroll
            for (int mi = 0; mi < 4; ++mi) {
                int r = wm + mi * 16 + ln;
                int g = ((ks >> 3) + q) ^ (r & 7);   // swizzled granule
                a[mi] = *(const bf16x8*)(&Xs[p][r * 64 + g * 8]);
            }
#pragma unroll
            for (int ni = 0; ni < 4; ++ni) {
                int r = wn + ni * 16 + ln;
                int g = ((ks >> 3) + q) ^ (r & 7);
                b[ni] = *(const bf16x8*)(&Ws[p][r * 64 + g * 8]);
            }
#pragma unroll
            for (int mi = 0; mi < 4; ++mi)
#pragma unroll
                for (int ni = 0; ni < 4; ++ni)
                    acc[mi][ni] = __builtin_amdgcn_mfma_f32_16x16x32_bf16(
                        a[mi], b[ni], acc[mi][ni], 0, 0, 0);
        }
        __syncthreads();            // all reads of parity p done before restage
    }
    // epilogue: C/D layout col(=n) = ln, row(=m) = q*4+reg
    {
        unsigned short* dst = (n0 < 256) ? Kb : Vb;  // uniform per block
        const int d0 = (n0 & 255) + wn;
#pragma unroll
        for (int mi = 0; mi < 4; ++mi)
#pragma unroll
            for (int ni = 0; ni < 4; ++ni) {
                int d = d0 + ni * 16 + ln;
#pragma unroll
                for (int r = 0; r < 4; ++r) {
                    int m = m0 + wm + mi * 16 + q * 4 + r;
                    dst[m * 256 + d] = f2bf(acc[mi][ni][r]);
                }
            }
    }
}

// -----------------------------------------------------------------------------
// Phase 2: fused S = Q·K^T, P = Wout·V^T, softmax-weighted reduce over t.
// Round-17: r11's shared-staging structure with the register cap FIXED.
// r11 failed solely because __launch_bounds__(512,4) clamped VGPR to 64 ->
// wholesale aQ/aW spill (WRITE_SIZE 0.5->106 MB, 253 us). (512,2) mirrors
// r5's verified constraint (cap 256); body needs ~120 VGPR -> no spill, and
// at <=128 VGPR + 64 KB LDS the HW fits 2 blocks/CU = 4 waves/SIMD.
// Structure: 8 waves x 32 l = 256 l per block; ONE double-buffered staging
// copy serves all 8 waves (per-wave DMA halves vs r5); grid = 16 b x 32.
// Per-wave body identical to r5 (16x16x32, 8 indep acc chains, XOR swizzle,
// vmcnt(0) drain + barrier + prefetch). Output bit-identical to r5.
// -----------------------------------------------------------------------------
__global__ __launch_bounds__(512, 2) void attn_fused(const unsigned short* __restrict__ Qb,
                                                     const unsigned short* __restrict__ Wob,
                                                     const unsigned short* __restrict__ Kb,
                                                     const unsigned short* __restrict__ Vb,
                                                     const int* __restrict__ mask,
                                                     const float* __restrict__ bias,
                                                     float* __restrict__ out) {
    __shared__ unsigned short Ks[2][8192];  // 32 rows x 256 ushorts, XOR-swizzled granules
    __shared__ unsigned short Vs[2][8192];
    const int bid = blockIdx.x;
    const int bb = bid >> 5;             // batch
    const int l0 = (bid & 31) * 256;     // l-tile origin (256 l per block)
    const int tid = threadIdx.x;
    const int lane = tid & 63, w = tid >> 6;   // w = 32-l strip 0..7
    const int q = lane >> 4, ln = lane & 15;
    const int hi = lane >> 5, lo = lane & 31;  // DMA row-half / granule slot

    // DMA-stage chunk c (32t x 256d of K and V) into parity c&1.
    // 32 row-pair groups (K: 0..15, V: 16..31); each of 8 waves issues 4.
    // Group g covers rows 2g,2g+1 (1 KB contiguous); lane i fetches source
    // granule (lo ^ t) of row t = 2g+hi so LDS granule gl holds gd = gl ^ t.
    auto stage = [&](int c) {
        const int p = c & 1;
        const int rbase = bb * 512 + c * 32;
#pragma unroll
        for (int j = 0; j < 4; ++j) {
            int gid = w * 4 + j;        // wave-uniform, 0..31
            int g = gid & 15;           // row-pair index
            const unsigned short* srcb = (gid < 16) ? Kb : Vb;
            unsigned short* dstb = (gid < 16) ? &Ks[p][0] : &Vs[p][0];
            int tl = 2 * g + hi;        // local t-row 0..31
            gld_lds16(srcb + (size_t)(rbase + tl) * 256 + ((lo ^ tl) << 3),
                      dstb + g * 512);
        }
    };
    stage(0);   // overlaps the register prologue below

    // Prologue 1: per-lane mask bits. t = 16*(2c+ni) + ln  ->  bit j = 2c+ni.
    unsigned mbits = 0;
    {
        const int* mrow = mask + bb * 512;
#pragma unroll
        for (int j = 0; j < 32; ++j)
            mbits |= (mrow[j * 16 + ln] != 0 ? 1u : 0u) << j;
    }

    // Prologue 2: A-fragments for 32 l-rows x full d=256 (8 k-steps) in regs.
    bf16x8 aQ[2][8], aW[2][8];
#pragma unroll
    for (int mi = 0; mi < 2; ++mi) {
        const int row = (l0 + w * 32 + mi * 16 + ln) * 256;
#pragma unroll
        for (int kk = 0; kk < 8; ++kk) {
            aQ[mi][kk] = *(const bf16x8*)(&Qb[row + kk * 32 + q * 8]);
            aW[mi][kk] = *(const bf16x8*)(&Wob[row + kk * 32 + q * 8]);
        }
    }

    float num[2][4], den[2][4];
#pragma unroll
    for (int mi = 0; mi < 2; ++mi)
#pragma unroll
        for (int r = 0; r < 4; ++r) { num[mi][r] = 0.f; den[mi][r] = 0.f; }

#pragma unroll 1
    for (int c = 0; c < 16; ++c) {
        // Hard guarantee: all in-flight global_load_lds DMAs (stage(c)) landed
        // before the barrier (round-3 race fix; verified round 4/5).
        asm volatile("s_waitcnt vmcnt(0)" ::: "memory");
        __syncthreads();           // chunk c ready; parity c&1 reusable
        if (c < 15) stage(c + 1);  // prefetch lands during compute below
        const int p = c & 1;

        f32x4 Sa[2][2], Pa[2][2];
#pragma unroll
        for (int mi = 0; mi < 2; ++mi)
#pragma unroll
            for (int ni = 0; ni < 2; ++ni) {
                Sa[mi][ni] = f32x4{0.f, 0.f, 0.f, 0.f};
                Pa[mi][ni] = f32x4{0.f, 0.f, 0.f, 0.f};
            }

#pragma unroll
        for (int kk = 0; kk < 8; ++kk) {
            bf16x8 bK[2], bV[2];
#pragma unroll
            for (int ni = 0; ni < 2; ++ni) {
                const int t = ni * 16 + ln;                       // row in chunk
                const int off = t * 256 + (((kk * 4 + q) ^ t) << 3);  // swizzled granule
                bK[ni] = *(const bf16x8*)(&Ks[p][off]);
                bV[ni] = *(const bf16x8*)(&Vs[p][off]);
            }
#pragma unroll
            for (int mi = 0; mi < 2; ++mi)
#pragma unroll
                for (int ni = 0; ni < 2; ++ni) {
                    Sa[mi][ni] = __builtin_amdgcn_mfma_f32_16x16x32_bf16(
                        aQ[mi][kk], bK[ni], Sa[mi][ni], 0, 0, 0);
                    Pa[mi][ni] = __builtin_amdgcn_mfma_f32_16x16x32_bf16(
                        aW[mi][kk], bV[ni], Pa[mi][ni], 0, 0, 0);
                }
        }
        // softmax partials. D layout: col(=t) = ln, row(=l) = q*4+r.
        // Q pre-scaled by log2(e)/16; S small: exp2 w/o max-shift is exact.
#pragma unroll
        for (int ni = 0; ni < 2; ++ni) {
            bool ok = (mbits >> (c * 2 + ni)) & 1u;
#pragma unroll
            for (int mi = 0; mi < 2; ++mi)
#pragma unroll
                for (int r = 0; r < 4; ++r) {
                    float e = ok ? __builtin_amdgcn_exp2f(Sa[mi][ni][r]) : 0.0f;
                    den[mi][r] += e;
                    num[mi][r] += e * Pa[mi][ni][r];
                }
        }
    }

    // reduce over the 16 t-columns (lanes ln) of each quad group; each wave
    // covered all 512 t, so no cross-wave reduction is needed.
#pragma unroll
    for (int mi = 0; mi < 2; ++mi)
#pragma unroll
        for (int r = 0; r < 4; ++r) {
            float n_ = num[mi][r], d_ = den[mi][r];
#pragma unroll
            for (int o = 1; o < 16; o <<= 1) {
                n_ += __shfl_xor(n_, o);
                d_ += __shfl_xor(d_, o);
            }
            if (ln == 0) {
                int l = l0 + w * 32 + mi * 16 + q * 4 + r;
                out[bb * 8192 + l] = n_ / d_ + bias[l];
            }
        }
}

extern "C" void kernel_launch(void* const* d_in, const int* in_sizes, int n_in,
                              void* d_out, int out_size, void* d_ws, size_t ws_size,
                              hipStream_t stream) {
    const float* X    = (const float*)d_in[0];  // [16,512,1024]
    const int*   mask = (const int*)d_in[1];    // [16,512]
    const float* Q    = (const float*)d_in[2];  // [8192,256]
    const float* Wk   = (const float*)d_in[3];  // [256,1024]
    const float* Wv   = (const float*)d_in[4];  // [256,1024]
    const float* Wo   = (const float*)d_in[5];  // [8192,256]
    const float* bias = (const float*)d_in[6];  // [8192]
    float* out = (float*)d_out;                 // [16,8192]

    unsigned short* Xb   = (unsigned short*)d_ws;          // 8,388,608 elems
    unsigned short* Qb   = Xb + 8388608ull;                // 2,097,152 (Q * log2e/16)
    unsigned short* Wob  = Qb + 2097152ull;                // 2,097,152
    unsigned short* Wkvb = Wob + 2097152ull;               // 524,288 (Wk 0-255, Wv 256-511)
    unsigned short* Kb   = Wkvb + 524288ull;               // 2,097,152
    unsigned short* Vb   = Kb + 2097152ull;                // 2,097,152  (total ~34.6 MB)

    cvt_all<<<dim3(3200), 256, 0, stream>>>(X, Q, Wo, Wk, Wv, Xb);
    kv_gemm<<<dim3(256), 256, 0, stream>>>(Xb, Wkvb, Kb, Vb);
    attn_fused<<<dim3(512), 512, 0, stream>>>(Qb, Wob, Kb, Vb, mask, bias, out);
}

// Round 13
// 194.070 us; speedup vs baseline: 1.8886x; 1.0027x over previous
//
#include <hip/hip_runtime.h>
#include <hip/hip_bf16.h>

// Problem constants: B=16, T=512, H=1024, L=8192, D=256
// logits[b,l] = sum_t softmax_t(Q[l]·K[b,t]/16) * (Wout[l]·V[b,t]) + bias[l]

typedef __bf16 bf16x8 __attribute__((ext_vector_type(8)));
typedef float f32x4 __attribute__((ext_vector_type(4)));

__device__ __forceinline__ unsigned short f2bf(float f) {
    // round-to-nearest-even fp32 -> bf16 (finite inputs only)
    unsigned int u = __builtin_bit_cast(unsigned int, f);
    unsigned int lsb = (u >> 16) & 1u;
    u += 0x7fffu + lsb;
    return (unsigned short)(u >> 16);
}

// async global->LDS DMA: each lane contributes 16 B; LDS dest = wave-uniform
// base + lane*16 (m104/m108). Global source IS per-lane -> swizzled layouts
// are achieved by pre-swizzling the per-lane source address (rule #21).
__device__ __forceinline__ void gld_lds16(const void* g, void* l) {
    __builtin_amdgcn_global_load_lds((__attribute__((address_space(1))) void*)g,
                                     (__attribute__((address_space(3))) void*)l,
                                     16, 0, 0);
}

// -----------------------------------------------------------------------------
// Fused fp32->bf16 conversion for all five tensors in one launch.
// Q segment is pre-scaled by log2(e)/16: folds the softmax 1/sqrt(D) scale AND
// the exp->exp2 conversion out of the attention inner loop (verified r2/r5).
// Segments (float4 units): X 2097152 | Q 524288 | Wo 524288 | Wk 65536 | Wv 65536
// -----------------------------------------------------------------------------
__global__ __launch_bounds__(256) void cvt_all(const float* __restrict__ X,
                                               const float* __restrict__ Q,
                                               const float* __restrict__ Wo,
                                               const float* __restrict__ Wk,
                                               const float* __restrict__ Wv,
                                               unsigned short* __restrict__ dst) {
    int base = blockIdx.x * 1024 + threadIdx.x;
#pragma unroll
    for (int r = 0; r < 4; ++r) {
        int idx = base + r * 256;  // float4 index, < 3276800
        const float* src;
        int off;
        float s = 1.0f;
        if (idx < 2097152)      { src = X;  off = idx; }
        else if (idx < 2621440) { src = Q;  off = idx - 2097152; s = 0.09016844006f; }
        else if (idx < 3145728) { src = Wo; off = idx - 2621440; }
        else if (idx < 3211264) { src = Wk; off = idx - 3145728; }
        else                    { src = Wv; off = idx - 3211264; }
        float4 v = ((const float4*)src)[off];
        ushort4 o;
        o.x = f2bf(v.x * s); o.y = f2bf(v.y * s);
        o.z = f2bf(v.z * s); o.w = f2bf(v.w * s);
        ((ushort4*)dst)[idx] = o;
    }
}

// -----------------------------------------------------------------------------
// Phase 1: K,V projection (r9 version — DMA-staged, double-buffered, verified).
// C[m][n] = sum_h X[m][h]*Wkv[n][h]; M=8192, N=512, K=1024.
// Tile 128x128, grid 64x4, 4 waves 2x2, LDS 2x(16+16) KB, XOR granule swizzle.
// -----------------------------------------------------------------------------
__global__ __launch_bounds__(256) void kv_gemm(const unsigned short* __restrict__ Xb,
                                               const unsigned short* __restrict__ Wb,
                                               unsigned short* __restrict__ Kb,
                                               unsigned short* __restrict__ Vb) {
    __shared__ unsigned short Xs[2][128 * 64];  // row-major, granule-swizzled
    __shared__ unsigned short Ws[2][128 * 64];
    const int bid = blockIdx.x;
    const int nt = bid & 3, mt = bid >> 2;
    const int m0 = mt * 128, n0 = nt * 128;
    const int tid = threadIdx.x;
    const int lane = tid & 63, w = tid >> 6;
    const int q = lane >> 4, ln = lane & 15;
    const int wm = (w & 1) * 64, wn = (w >> 1) * 64;
    const int lrow = lane >> 3;            // 0..7 within the 8-row DMA span
    const int gsw  = (lane & 7) ^ lrow;    // pre-swizzled source granule

    f32x4 acc[4][4];
#pragma unroll
    for (int mi = 0; mi < 4; ++mi)
#pragma unroll
        for (int ni = 0; ni < 4; ++ni) acc[mi][ni] = f32x4{0.f, 0.f, 0.f, 0.f};

    auto stage = [&](int hc) {
        const int p = hc & 1;
        const int h0 = hc * 64;
#pragma unroll
        for (int j = 0; j < 4; ++j) {
            int slot = w * 4 + j;          // wave-uniform, 0..15
            int r = slot * 8 + lrow;       // local row 0..127
            gld_lds16(Xb + (size_t)(m0 + r) * 1024 + h0 + gsw * 8,
                      &Xs[p][slot * 512]);
            gld_lds16(Wb + (size_t)(n0 + r) * 1024 + h0 + gsw * 8,
                      &Ws[p][slot * 512]);
        }
    };
    stage(0);

#pragma unroll 1
    for (int hc = 0; hc < 16; ++hc) {
        asm volatile("s_waitcnt vmcnt(0)" ::: "memory");
        __syncthreads();            // chunk hc landed; parity hc&1 reusable
        if (hc < 15) stage(hc + 1); // prefetch lands during compute below
        const int p = hc & 1;
#pragma unroll
        for (int ks = 0; ks < 64; ks += 32) {
            bf16x8 a[4], b[4];
#pragma unroll
            for (int mi = 0; mi < 4; ++mi) {
                int r = wm + mi * 16 + ln;
                int g = ((ks >> 3) + q) ^ (r & 7);   // swizzled granule
                a[mi] = *(const bf16x8*)(&Xs[p][r * 64 + g * 8]);
            }
#pragma unroll
            for (int ni = 0; ni < 4; ++ni) {
                int r = wn + ni * 16 + ln;
                int g = ((ks >> 3) + q) ^ (r & 7);
                b[ni] = *(const bf16x8*)(&Ws[p][r * 64 + g * 8]);
            }
#pragma unroll
            for (int mi = 0; mi < 4; ++mi)
#pragma unroll
                for (int ni = 0; ni < 4; ++ni)
                    acc[mi][ni] = __builtin_amdgcn_mfma_f32_16x16x32_bf16(
                        a[mi], b[ni], acc[mi][ni], 0, 0, 0);
        }
        __syncthreads();            // all reads of parity p done before restage
    }
    // epilogue: C/D layout col(=n) = ln, row(=m) = q*4+reg
    {
        unsigned short* dst = (n0 < 256) ? Kb : Vb;  // uniform per block
        const int d0 = (n0 & 255) + wn;
#pragma unroll
        for (int mi = 0; mi < 4; ++mi)
#pragma unroll
            for (int ni = 0; ni < 4; ++ni) {
                int d = d0 + ni * 16 + ln;
#pragma unroll
                for (int r = 0; r < 4; ++r) {
                    int m = m0 + wm + mi * 16 + q * 4 + r;
                    dst[m * 256 + d] = f2bf(acc[mi][ni][r]);
                }
            }
    }
}

// -----------------------------------------------------------------------------
// Phase 2: fused S = Q·K^T, P = Wout·V^T, softmax-weighted reduce over t.
// Round-18 (occupancy via MORE, SMALLER blocks): r12 showed 512-thread blocks
// do NOT co-schedule 2/CU (occupancy stuck 21%). This build halves the t-chunk
// 32 -> 16: LDS 64 -> 32 KB/block, so LDS admits 5 blocks/CU and VGPR (120 x 4
// waves/SIMD = 480 <= 512) admits 4 -> 4 independent barrier groups per CU.
// During any block's DMA-drain+barrier, three other blocks issue ds_read/MFMA
// -> fills the measured ~48% idle LDS-port time. Same total bytes, same MFMA
// count, same per-l accumulation order -> output bit-identical to r5.
// Per-chunk: 16 DMAs (4/wave), 8 ds_read pairs, 32 MFMA (4 indep acc chains,
// 8-deep — r10's 2-chain latency trap avoided). 32 chunks. Schedule per chunk
// unchanged from r5: vmcnt(0) drain + barrier + prefetch-next.
// Block = 4 waves x 32 l = 128 l; grid = 16 b x 64 = 1024 blocks.
// -----------------------------------------------------------------------------
__global__ __launch_bounds__(256, 2) void attn_fused(const unsigned short* __restrict__ Qb,
                                                     const unsigned short* __restrict__ Wob,
                                                     const unsigned short* __restrict__ Kb,
                                                     const unsigned short* __restrict__ Vb,
                                                     const int* __restrict__ mask,
                                                     const float* __restrict__ bias,
                                                     float* __restrict__ out) {
    __shared__ unsigned short Ks[2][4096];  // 16 rows x 256 ushorts, XOR-swizzled granules
    __shared__ unsigned short Vs[2][4096];
    const int bid = blockIdx.x;
    const int bb = bid >> 6;             // batch
    const int l0 = (bid & 63) * 128;     // l-tile origin
    const int tid = threadIdx.x;
    const int lane = tid & 63, w = tid >> 6;   // w = 32-l strip 0..3
    const int q = lane >> 4, ln = lane & 15;
    const int hi = lane >> 5, lo = lane & 31;  // DMA row-half / granule slot

    // DMA-stage chunk c (16t x 256d of K and V) into parity c&1.
    // 16 row-pair groups (K: 0..7, V: 8..15); each of 4 waves issues 4.
    // Group g covers rows 2g,2g+1 (1 KB contiguous); lane i fetches source
    // granule (lo ^ t) of row t = 2g+hi so LDS granule gl holds gd = gl ^ t.
    auto stage = [&](int c) {
        const int p = c & 1;
        const int rbase = bb * 512 + c * 16;
#pragma unroll
        for (int j = 0; j < 4; ++j) {
            int gid = w * 4 + j;        // wave-uniform, 0..15
            int g = gid & 7;            // row-pair index
            const unsigned short* srcb = (gid < 8) ? Kb : Vb;
            unsigned short* dstb = (gid < 8) ? &Ks[p][0] : &Vs[p][0];
            int tl = 2 * g + hi;        // local t-row 0..15
            gld_lds16(srcb + (size_t)(rbase + tl) * 256 + ((lo ^ tl) << 3),
                      dstb + g * 512);
        }
    };
    stage(0);   // overlaps the register prologue below

    // Prologue 1: per-lane mask bits. t = 16*c + ln  ->  bit c (32 chunks).
    unsigned mbits = 0;
    {
        const int* mrow = mask + bb * 512;
#pragma unroll
        for (int j = 0; j < 32; ++j)
            mbits |= (mrow[j * 16 + ln] != 0 ? 1u : 0u) << j;
    }

    // Prologue 2: A-fragments for 32 l-rows x full d=256 (8 k-steps) in regs.
    bf16x8 aQ[2][8], aW[2][8];
#pragma unroll
    for (int mi = 0; mi < 2; ++mi) {
        const int row = (l0 + w * 32 + mi * 16 + ln) * 256;
#pragma unroll
        for (int kk = 0; kk < 8; ++kk) {
            aQ[mi][kk] = *(const bf16x8*)(&Qb[row + kk * 32 + q * 8]);
            aW[mi][kk] = *(const bf16x8*)(&Wob[row + kk * 32 + q * 8]);
        }
    }

    float num[2][4], den[2][4];
#pragma unroll
    for (int mi = 0; mi < 2; ++mi)
#pragma unroll
        for (int r = 0; r < 4; ++r) { num[mi][r] = 0.f; den[mi][r] = 0.f; }

#pragma unroll 1
    for (int c = 0; c < 32; ++c) {
        // Hard guarantee: all in-flight global_load_lds DMAs (stage(c)) landed
        // before the barrier (round-3 race fix; verified round 4/5).
        asm volatile("s_waitcnt vmcnt(0)" ::: "memory");
        __syncthreads();           // chunk c ready; parity c&1 reusable
        if (c < 31) stage(c + 1);  // prefetch lands during compute below
        const int p = c & 1;

        f32x4 Sa[2], Pa[2];
#pragma unroll
        for (int mi = 0; mi < 2; ++mi) {
            Sa[mi] = f32x4{0.f, 0.f, 0.f, 0.f};
            Pa[mi] = f32x4{0.f, 0.f, 0.f, 0.f};
        }

#pragma unroll
        for (int kk = 0; kk < 8; ++kk) {
            const int t = ln;                                 // row in chunk
            const int off = t * 256 + (((kk * 4 + q) ^ t) << 3);  // swizzled granule
            bf16x8 bK = *(const bf16x8*)(&Ks[p][off]);
            bf16x8 bV = *(const bf16x8*)(&Vs[p][off]);
#pragma unroll
            for (int mi = 0; mi < 2; ++mi) {
                Sa[mi] = __builtin_amdgcn_mfma_f32_16x16x32_bf16(
                    aQ[mi][kk], bK, Sa[mi], 0, 0, 0);
                Pa[mi] = __builtin_amdgcn_mfma_f32_16x16x32_bf16(
                    aW[mi][kk], bV, Pa[mi], 0, 0, 0);
            }
        }
        // softmax partials. D layout: col(=t) = ln, row(=l) = q*4+r.
        // Q pre-scaled by log2(e)/16; S small: exp2 w/o max-shift is exact.
        {
            bool ok = (mbits >> c) & 1u;
#pragma unroll
            for (int mi = 0; mi < 2; ++mi)
#pragma unroll
                for (int r = 0; r < 4; ++r) {
                    float e = ok ? __builtin_amdgcn_exp2f(Sa[mi][r]) : 0.0f;
                    den[mi][r] += e;
                    num[mi][r] += e * Pa[mi][r];
                }
        }
    }

    // reduce over the 16 t-columns (lanes ln) of each quad group; each wave
    // covered all 512 t, so no cross-wave reduction is needed.
#pragma unroll
    for (int mi = 0; mi < 2; ++mi)
#pragma unroll
        for (int r = 0; r < 4; ++r) {
            float n_ = num[mi][r], d_ = den[mi][r];
#pragma unroll
            for (int o = 1; o < 16; o <<= 1) {
                n_ += __shfl_xor(n_, o);
                d_ += __shfl_xor(d_, o);
            }
            if (ln == 0) {
                int l = l0 + w * 32 + mi * 16 + q * 4 + r;
                out[bb * 8192 + l] = n_ / d_ + bias[l];
            }
        }
}

extern "C" void kernel_launch(void* const* d_in, const int* in_sizes, int n_in,
                              void* d_out, int out_size, void* d_ws, size_t ws_size,
                              hipStream_t stream) {
    const float* X    = (const float*)d_in[0];  // [16,512,1024]
    const int*   mask = (const int*)d_in[1];    // [16,512]
    const float* Q    = (const float*)d_in[2];  // [8192,256]
    const float* Wk   = (const float*)d_in[3];  // [256,1024]
    const float* Wv   = (const float*)d_in[4];  // [256,1024]
    const float* Wo   = (const float*)d_in[5];  // [8192,256]
    const float* bias = (const float*)d_in[6];  // [8192]
    float* out = (float*)d_out;                 // [16,8192]

    unsigned short* Xb   = (unsigned short*)d_ws;          // 8,388,608 elems
    unsigned short* Qb   = Xb + 8388608ull;                // 2,097,152 (Q * log2e/16)
    unsigned short* Wob  = Qb + 2097152ull;                // 2,097,152
    unsigned short* Wkvb = Wob + 2097152ull;               // 524,288 (Wk 0-255, Wv 256-511)
    unsigned short* Kb   = Wkvb + 524288ull;               // 2,097,152
    unsigned short* Vb   = Kb + 2097152ull;                // 2,097,152  (total ~34.6 MB)

    cvt_all<<<dim3(3200), 256, 0, stream>>>(X, Q, Wo, Wk, Wv, Xb);
    kv_gemm<<<dim3(256), 256, 0, stream>>>(Xb, Wkvb, Kb, Vb);
    attn_fused<<<dim3(1024), 256, 0, stream>>>(Qb, Wob, Kb, Vb, mask, bias, out);
}

// Round 14
// 191.971 us; speedup vs baseline: 1.9093x; 1.0109x over previous
//
#include <hip/hip_runtime.h>
#include <hip/hip_bf16.h>

// Problem constants: B=16, T=512, H=1024, L=8192, D=256
// logits[b,l] = sum_t softmax_t(Q[l]·K[b,t]/16) * (Wout[l]·V[b,t]) + bias[l]
//
// FINAL CONFIGURATION (session best, measured 190.7 us total / 82.2 us attn):
// every structural alternative was measured and regressed —
//   r2  mi=4 (64 l/wave):        register wall, compiler re-loads A in-loop
//   r6  counted-vmcnt 2-barrier: -8% (coarse phase-split, m196 anti-pattern)
//   r8  de-staged direct L2:     -3.1x (scattered 64-B segs, L1-transaction
//       bound; K/V L2-residency does NOT make staging removable)
//   r10 32x32x16 MFMA:           -7% (2 dependent acc chains expose MFMA lat)
//   r12 512-thd shared staging:  neutral (occupancy pinned ~8 waves/CU)
//   r13 16-t chunks (32 KB LDS): -9% (2x barrier count, occupancy unchanged)
// Verified wins kept: XOR granule swizzle (conflicts 8.39M -> 0), contiguous
// 1 KB DMA (r4's scatter cost +9 us), exp2 with log2(e)/16 folded into Q,
// vmcnt(0) drain before barrier (r3 race fix), per-lane mask bitmask.

typedef __bf16 bf16x8 __attribute__((ext_vector_type(8)));
typedef float f32x4 __attribute__((ext_vector_type(4)));

__device__ __forceinline__ unsigned short f2bf(float f) {
    // round-to-nearest-even fp32 -> bf16 (finite inputs only)
    unsigned int u = __builtin_bit_cast(unsigned int, f);
    unsigned int lsb = (u >> 16) & 1u;
    u += 0x7fffu + lsb;
    return (unsigned short)(u >> 16);
}

// async global->LDS DMA: each lane contributes 16 B; LDS dest = wave-uniform
// base + lane*16 (m104/m108). Global source IS per-lane -> swizzled layouts
// are achieved by pre-swizzling the per-lane source address (rule #21).
__device__ __forceinline__ void gld_lds16(const void* g, void* l) {
    __builtin_amdgcn_global_load_lds((__attribute__((address_space(1))) void*)g,
                                     (__attribute__((address_space(3))) void*)l,
                                     16, 0, 0);
}

// -----------------------------------------------------------------------------
// Fused fp32->bf16 conversion for all five tensors in one launch.
// Q segment is pre-scaled by log2(e)/16: folds the softmax 1/sqrt(D) scale AND
// the exp->exp2 conversion out of the attention inner loop (verified r2/r5:
// absmax 2.441406e-4, identical to the expf path).
// Segments (float4 units): X 2097152 | Q 524288 | Wo 524288 | Wk 65536 | Wv 65536
// -----------------------------------------------------------------------------
__global__ __launch_bounds__(256) void cvt_all(const float* __restrict__ X,
                                               const float* __restrict__ Q,
                                               const float* __restrict__ Wo,
                                               const float* __restrict__ Wk,
                                               const float* __restrict__ Wv,
                                               unsigned short* __restrict__ dst) {
    int base = blockIdx.x * 1024 + threadIdx.x;
#pragma unroll
    for (int r = 0; r < 4; ++r) {
        int idx = base + r * 256;  // float4 index, < 3276800
        const float* src;
        int off;
        float s = 1.0f;
        if (idx < 2097152)      { src = X;  off = idx; }
        else if (idx < 2621440) { src = Q;  off = idx - 2097152; s = 0.09016844006f; }
        else if (idx < 3145728) { src = Wo; off = idx - 2621440; }
        else if (idx < 3211264) { src = Wk; off = idx - 3145728; }
        else                    { src = Wv; off = idx - 3211264; }
        float4 v = ((const float4*)src)[off];
        ushort4 o;
        o.x = f2bf(v.x * s); o.y = f2bf(v.y * s);
        o.z = f2bf(v.z * s); o.w = f2bf(v.w * s);
        ((ushort4*)dst)[idx] = o;
    }
}

// -----------------------------------------------------------------------------
// Phase 1: K,V projection. C[m][n] = sum_h X[m][h] * Wkv[n][h]
//   M = B*T = 8192, N = 512 (n<256 -> K dim d=n; else V dim d=n-256), K = 1024
// Tile: 128m x 128n per block (grid 64x4), 4 waves in 2x2, wave = 64m x 64n.
// r5 version (best measured total). r9's DMA-staged rebuild measured neutral
// (kv_gemm is HBM-staging-bound at ~25 us either way; 1 block/CU, grid 256).
// -----------------------------------------------------------------------------
__global__ __launch_bounds__(256) void kv_gemm(const unsigned short* __restrict__ Xb,
                                               const unsigned short* __restrict__ Wb,
                                               unsigned short* __restrict__ Kb,
                                               unsigned short* __restrict__ Vb) {
    __shared__ unsigned short Xs[128 * 72];  // 64-wide h-chunk, stride 72 (pad 8)
    __shared__ unsigned short Ws[128 * 72];
    const int bid = blockIdx.x;
    const int nt = bid & 3, mt = bid >> 2;
    const int m0 = mt * 128, n0 = nt * 128;
    const int tid = threadIdx.x;
    const int lane = tid & 63, w = tid >> 6;
    const int q = lane >> 4, ln = lane & 15;
    const int wm = (w & 1) * 64, wn = (w >> 1) * 64;

    f32x4 acc[4][4];
#pragma unroll
    for (int mi = 0; mi < 4; ++mi)
#pragma unroll
        for (int ni = 0; ni < 4; ++ni) acc[mi][ni] = f32x4{0.f, 0.f, 0.f, 0.f};

#pragma unroll 1
    for (int h0 = 0; h0 < 1024; h0 += 64) {
#pragma unroll
        for (int i = 0; i < 4; ++i) {  // stage X and Wkv tiles: 128 rows x 64 h each
            int c = tid + i * 256;
            int row = c >> 3, off = (c & 7) << 3;
            *(uint4*)(&Xs[row * 72 + off]) = *(const uint4*)(&Xb[(m0 + row) * 1024 + h0 + off]);
            *(uint4*)(&Ws[row * 72 + off]) = *(const uint4*)(&Wb[(n0 + row) * 1024 + h0 + off]);
        }
        __syncthreads();
#pragma unroll
        for (int ks = 0; ks < 64; ks += 32) {
            bf16x8 a[4], b[4];
#pragma unroll
            for (int mi = 0; mi < 4; ++mi)
                a[mi] = *(const bf16x8*)(&Xs[(wm + mi * 16 + ln) * 72 + ks + q * 8]);
#pragma unroll
            for (int ni = 0; ni < 4; ++ni)
                b[ni] = *(const bf16x8*)(&Ws[(wn + ni * 16 + ln) * 72 + ks + q * 8]);
#pragma unroll
            for (int mi = 0; mi < 4; ++mi)
#pragma unroll
                for (int ni = 0; ni < 4; ++ni)
                    acc[mi][ni] = __builtin_amdgcn_mfma_f32_16x16x32_bf16(
                        a[mi], b[ni], acc[mi][ni], 0, 0, 0);
        }
        __syncthreads();
    }
    // epilogue: C/D layout col(=n) = ln, row(=m) = q*4+reg
    {
        unsigned short* dst = (n0 < 256) ? Kb : Vb;  // uniform per block
        const int d0 = (n0 & 255) + wn;
#pragma unroll
        for (int mi = 0; mi < 4; ++mi)
#pragma unroll
            for (int ni = 0; ni < 4; ++ni) {
                int d = d0 + ni * 16 + ln;
#pragma unroll
                for (int r = 0; r < 4; ++r) {
                    int m = m0 + wm + mi * 16 + q * 4 + r;
                    dst[m * 256 + d] = f2bf(acc[mi][ni][r]);
                }
            }
    }
}

// -----------------------------------------------------------------------------
// Phase 2: fused S = Q·K^T, P = Wout·V^T, softmax-weighted reduce over t.
// r5 kernel exactly — the measured session optimum (82.2 us, MfmaUtil 36%,
// conflicts 0, no spill). Structure: mi=2 (32 l/wave, the VGPR wall), 4 waves,
// 2 blocks/CU, 32-t double-buffered chunks, contiguous 1 KB DMAs with XOR
// granule swizzle (conflict-free by 8-lane-phase argument), vmcnt(0) drain +
// single barrier + prefetch-next-during-compute. Measured phase time ≈
// serial(MFMA 2480 cyc, LDS 3600 cyc) — the m233 2-phase structure; all
// documented escapes measured null-or-negative at this wave count (see header).
// Block = 4 waves x 32 l = 128 l; grid = 16 b x 64 = 1024 blocks.
// -----------------------------------------------------------------------------
__global__ __launch_bounds__(256, 2) void attn_fused(const unsigned short* __restrict__ Qb,
                                                     const unsigned short* __restrict__ Wob,
                                                     const unsigned short* __restrict__ Kb,
                                                     const unsigned short* __restrict__ Vb,
                                                     const int* __restrict__ mask,
                                                     const float* __restrict__ bias,
                                                     float* __restrict__ out) {
    __shared__ unsigned short Ks[2][8192];  // 32 rows x 256 ushorts, XOR-swizzled granules
    __shared__ unsigned short Vs[2][8192];
    const int bid = blockIdx.x;
    const int bb = bid >> 6;             // batch
    const int l0 = (bid & 63) * 128;     // l-tile origin
    const int tid = threadIdx.x;
    const int lane = tid & 63, w = tid >> 6;   // w = 32-l strip 0..3
    const int q = lane >> 4, ln = lane & 15;
    const int hi = lane >> 5, lo = lane & 31;  // DMA row-half / granule slot

    // DMA-stage chunk c (32t x 256d of K and V) into parity c&1.
    // 32 row-pair groups (K: 0..15, V: 16..31); each of 4 waves issues 8.
    // Group g covers rows 2g,2g+1 (1 KB contiguous); lane i fetches source
    // granule (lo ^ t) of row t = 2g+hi so LDS granule gl holds gd = gl ^ t.
    auto stage = [&](int c) {
        const int p = c & 1;
        const int rbase = bb * 512 + c * 32;
#pragma unroll
        for (int j = 0; j < 8; ++j) {
            int gid = w * 8 + j;        // wave-uniform, 0..31
            int g = gid & 15;           // row-pair index
            const unsigned short* srcb = (gid < 16) ? Kb : Vb;
            unsigned short* dstb = (gid < 16) ? &Ks[p][0] : &Vs[p][0];
            int tl = 2 * g + hi;        // local t-row 0..31
            gld_lds16(srcb + (size_t)(rbase + tl) * 256 + ((lo ^ tl) << 3),
                      dstb + g * 512);
        }
    };
    stage(0);   // overlaps the register prologue below

    // Prologue 1: per-lane mask bits. t = 16*(2c+ni) + ln  ->  bit j = 2c+ni.
    unsigned mbits = 0;
    {
        const int* mrow = mask + bb * 512;
#pragma unroll
        for (int j = 0; j < 32; ++j)
            mbits |= (mrow[j * 16 + ln] != 0 ? 1u : 0u) << j;
    }

    // Prologue 2: A-fragments for 32 l-rows x full d=256 (8 k-steps) in regs.
    bf16x8 aQ[2][8], aW[2][8];
#pragma unroll
    for (int mi = 0; mi < 2; ++mi) {
        const int row = (l0 + w * 32 + mi * 16 + ln) * 256;
#pragma unroll
        for (int kk = 0; kk < 8; ++kk) {
            aQ[mi][kk] = *(const bf16x8*)(&Qb[row + kk * 32 + q * 8]);
            aW[mi][kk] = *(const bf16x8*)(&Wob[row + kk * 32 + q * 8]);
        }
    }

    float num[2][4], den[2][4];
#pragma unroll
    for (int mi = 0; mi < 2; ++mi)
#pragma unroll
        for (int r = 0; r < 4; ++r) { num[mi][r] = 0.f; den[mi][r] = 0.f; }

#pragma unroll 1
    for (int c = 0; c < 16; ++c) {
        // Hard guarantee: all in-flight global_load_lds DMAs (stage(c)) landed
        // before the barrier (round-3 race fix; verified round 4/5).
        asm volatile("s_waitcnt vmcnt(0)" ::: "memory");
        __syncthreads();           // chunk c ready; parity c&1 reusable
        if (c < 15) stage(c + 1);  // prefetch lands during compute below
        const int p = c & 1;

        f32x4 Sa[2][2], Pa[2][2];
#pragma unroll
        for (int mi = 0; mi < 2; ++mi)
#pragma unroll
            for (int ni = 0; ni < 2; ++ni) {
                Sa[mi][ni] = f32x4{0.f, 0.f, 0.f, 0.f};
                Pa[mi][ni] = f32x4{0.f, 0.f, 0.f, 0.f};
            }

#pragma unroll
        for (int kk = 0; kk < 8; ++kk) {
            bf16x8 bK[2], bV[2];
#pragma unroll
            for (int ni = 0; ni < 2; ++ni) {
                const int t = ni * 16 + ln;                       // row in chunk
                const int off = t * 256 + (((kk * 4 + q) ^ t) << 3);  // swizzled granule
                bK[ni] = *(const bf16x8*)(&Ks[p][off]);
                bV[ni] = *(const bf16x8*)(&Vs[p][off]);
            }
#pragma unroll
            for (int mi = 0; mi < 2; ++mi)
#pragma unroll
                for (int ni = 0; ni < 2; ++ni) {
                    Sa[mi][ni] = __builtin_amdgcn_mfma_f32_16x16x32_bf16(
                        aQ[mi][kk], bK[ni], Sa[mi][ni], 0, 0, 0);
                    Pa[mi][ni] = __builtin_amdgcn_mfma_f32_16x16x32_bf16(
                        aW[mi][kk], bV[ni], Pa[mi][ni], 0, 0, 0);
                }
        }
        // softmax partials. D layout: col(=t) = ln, row(=l) = q*4+r.
        // Q pre-scaled by log2(e)/16; S small: exp2 w/o max-shift is exact.
#pragma unroll
        for (int ni = 0; ni < 2; ++ni) {
            bool ok = (mbits >> (c * 2 + ni)) & 1u;
#pragma unroll
            for (int mi = 0; mi < 2; ++mi)
#pragma unroll
                for (int r = 0; r < 4; ++r) {
                    float e = ok ? __builtin_amdgcn_exp2f(Sa[mi][ni][r]) : 0.0f;
                    den[mi][r] += e;
                    num[mi][r] += e * Pa[mi][ni][r];
                }
        }
    }

    // reduce over the 16 t-columns (lanes ln) of each quad group; each wave
    // covered all 512 t, so no cross-wave reduction is needed.
#pragma unroll
    for (int mi = 0; mi < 2; ++mi)
#pragma unroll
        for (int r = 0; r < 4; ++r) {
            float n_ = num[mi][r], d_ = den[mi][r];
#pragma unroll
            for (int o = 1; o < 16; o <<= 1) {
                n_ += __shfl_xor(n_, o);
                d_ += __shfl_xor(d_, o);
            }
            if (ln == 0) {
                int l = l0 + w * 32 + mi * 16 + q * 4 + r;
                out[bb * 8192 + l] = n_ / d_ + bias[l];
            }
        }
}

extern "C" void kernel_launch(void* const* d_in, const int* in_sizes, int n_in,
                              void* d_out, int out_size, void* d_ws, size_t ws_size,
                              hipStream_t stream) {
    const float* X    = (const float*)d_in[0];  // [16,512,1024]
    const int*   mask = (const int*)d_in[1];    // [16,512]
    const float* Q    = (const float*)d_in[2];  // [8192,256]
    const float* Wk   = (const float*)d_in[3];  // [256,1024]
    const float* Wv   = (const float*)d_in[4];  // [256,1024]
    const float* Wo   = (const float*)d_in[5];  // [8192,256]
    const float* bias = (const float*)d_in[6];  // [8192]
    float* out = (float*)d_out;                 // [16,8192]

    unsigned short* Xb   = (unsigned short*)d_ws;          // 8,388,608 elems
    unsigned short* Qb   = Xb + 8388608ull;                // 2,097,152 (Q * log2e/16)
    unsigned short* Wob  = Qb + 2097152ull;                // 2,097,152
    unsigned short* Wkvb = Wob + 2097152ull;               // 524,288 (Wk 0-255, Wv 256-511)
    unsigned short* Kb   = Wkvb + 524288ull;               // 2,097,152
    unsigned short* Vb   = Kb + 2097152ull;                // 2,097,152  (total ~34.6 MB)

    cvt_all<<<dim3(3200), 256, 0, stream>>>(X, Q, Wo, Wk, Wv, Xb);
    kv_gemm<<<dim3(256), 256, 0, stream>>>(Xb, Wkvb, Kb, Vb);
    attn_fused<<<dim3(1024), 256, 0, stream>>>(Qb, Wob, Kb, Vb, mask, bias, out);
}